// Round 22
// baseline (355.522 us; speedup 1.0000x reference)
//
#include <hip/hip_runtime.h>
#include <hip/hip_bf16.h>

#define LEAKY 0.2f

typedef __attribute__((ext_vector_type(8))) short bf16x8;
typedef __attribute__((ext_vector_type(4))) float f32x4;
typedef __attribute__((ext_vector_type(2))) float f32x2;

// ---------------- CSR build (chunk-16 padded), fused setup ----------------

__global__ __launch_bounds__(256) void k_init(int* cnt, int* bstart, int* hist, int n, int nb) {
    int i = blockIdx.x * 256 + threadIdx.x;
    if (i < n) cnt[i] = 1;            // self-loop pre-counted
    if (i < nb) bstart[i] = n;        // batch-boundary init
    if (i < 32) hist[i] = 0;          // degree-bucket histogram
}

// edge count + batch boundary detection (gE blocks >= gN)
__global__ __launch_bounds__(256) void k_count(const int* __restrict__ dst, int* cnt, int e,
                                               const int* __restrict__ bidx, int* bstart, int n) {
    int i = blockIdx.x * 256 + threadIdx.x;
    if (i < e) atomicAdd(&cnt[dst[i]], 1);
    if (i < n) {
        int b = bidx[i];
        if (i == 0 || bidx[i - 1] != b) atomicMin(&bstart[b], i);
    }
}

// block-wide inclusive scan of one value per thread (256 threads)
__device__ inline int block_incl_scan(int v, int* lds) {
    int lane = threadIdx.x & 63, wid = threadIdx.x >> 6;
    int s = v;
#pragma unroll
    for (int o = 1; o < 64; o <<= 1) { int t = __shfl_up(s, o); if (lane >= o) s += t; }
    if (lane == 63) lds[wid] = s;
    __syncthreads();
    int add = 0;
#pragma unroll
    for (int ww = 0; ww < 3; ++ww) if (ww < wid) add += lds[ww];
    return s + add;
}

__global__ __launch_bounds__(256) void k_scanA(const int* __restrict__ cnt, int* bsum, int n) {
    __shared__ int lds[4];
    int i = blockIdx.x * 256 + threadIdx.x;
    int v = (i < n) ? ((cnt[i] + 15) & ~15) : 0;
    int s = block_incl_scan(v, lds);
    if (threadIdx.x == 255) bsum[blockIdx.x] = s;
}

// scan of block sums + batch-boundary backward fill
__global__ __launch_bounds__(256) void k_scanB(int* bsum, int* boff, int nb,
                                               int* bstart, int n, int nbatch) {
    __shared__ int lds[4];
    int i = threadIdx.x;
    int v = (i < nb) ? bsum[i] : 0;
    int s = block_incl_scan(v, lds);
    if (i < nb) boff[i] = s - v;   // exclusive
    if (i == 0) {
        bstart[nbatch] = n;
        for (int b = nbatch - 1; b >= 0; --b)
            if (bstart[b] == n) bstart[b] = bstart[b + 1];
    }
}

// final scan + self-loop placement + cursor init + degree histogram (LDS-aggregated)
__global__ __launch_bounds__(256) void k_scanC(const int* __restrict__ cnt, const int* __restrict__ boff,
                                               int* row_ptr, int* csr, int* cursor, int* hist, int n) {
    __shared__ int lds[4];
    __shared__ int lh[32];
    int tid = threadIdx.x;
    if (tid < 32) lh[tid] = 0;
    int i = blockIdx.x * 256 + tid;
    int v = (i < n) ? ((cnt[i] + 15) & ~15) : 0;
    int s = block_incl_scan(v, lds) + boff[blockIdx.x];
    __syncthreads();
    if (i < n) {
        int excl = s - v;             // row_ptr[i]
        row_ptr[i + 1] = s;
        csr[excl] = i;                // self-loop first
        cursor[i] = excl + 1;
        atomicAdd(&lh[min(v >> 4, 31)], 1);   // LDS atomic
    }
    if (i == 0) row_ptr[0] = 0;
    __syncthreads();
    if (tid < 32 && lh[tid]) atomicAdd(&hist[tid], lh[tid]);
}

__global__ __launch_bounds__(256) void k_scatter(const int* __restrict__ src, const int* __restrict__ dst,
                                                 int* cursor, int* csr, int e) {
    int i = blockIdx.x * 256 + threadIdx.x;
    if (i < e) { int p = atomicAdd(&cursor[dst[i]], 1); csr[p] = src[i]; }
}

// exclusive scan of the 32-bucket histogram -> bucket cursors
__global__ void k_bscan(const int* __restrict__ hist, int* bcur) {
    int run = 0;
    for (int b = 0; b < 32; ++b) { bcur[b] = run; run += hist[b]; }
}

// pad slots + degree-bucketed permutation via two-level counting sort
__global__ __launch_bounds__(256) void k_pad(const int* __restrict__ row_ptr, const int* __restrict__ cursor,
                                             int* csr, int* bcur, int* perm, int n) {
    __shared__ int lh[32];    // block-local bucket counts
    __shared__ int lbase[32]; // reserved global base per bucket
    int tid = threadIdx.x;
    if (tid < 32) lh[tid] = 0;
    __syncthreads();
    int i = blockIdx.x * 256 + tid;
    int bkt = 0, lpos = 0, b0 = 0, p = 0, e = 0;
    if (i < n) {
        b0 = row_ptr[i]; p = cursor[i]; e = row_ptr[i + 1];
        bkt = min((e - b0) >> 4, 31);
        lpos = atomicAdd(&lh[bkt], 1);        // LDS atomic (fast)
    }
    __syncthreads();
    if (tid < 32 && lh[tid]) lbase[tid] = atomicAdd(&bcur[tid], lh[tid]);
    __syncthreads();
    if (i < n) {
        perm[lbase[bkt] + lpos] = i;
        int v = i | 0x80000000;
        for (; p < e; ++p) csr[p] = v;
    }
}

// round-nearest-even f32 -> bf16 (as ushort)
__device__ inline unsigned short bf16r(float x) {
    unsigned int u = __float_as_uint(x);
    u += 0x7fffu + ((u >> 16) & 1u);
    return (unsigned short)(u >> 16);
}

// round-nearest-even pack of two f32 into one uint (2×bf16, lo|hi<<16)
__device__ inline unsigned int bfpair(float lo, float hi) {
    unsigned int ul = __float_as_uint(lo); ul += 0x7fffu + ((ul >> 16) & 1u);
    unsigned int uh = __float_as_uint(hi); uh += 0x7fffu + ((uh >> 16) & 1u);
    return (ul >> 16) | (uh & 0xffff0000u);
}

// ---------------- MFMA GEMM + attention logits (batched over all T snapshots) ----------------
// OPERAND-SWAPPED: D = mfma(W_frag, X_frag). Wt in LDS with XOR-swizzled 16-B chunks:
// chunk(n, kg) = n*16 + (kg ^ (n&15))  [kg = k/8]. Old pad-136 layout had word-stride
// 68 ≡ 4 (mod 32) -> 8-way bank conflict on every ds_read_b128 (1.6M conflicts, 
// MfmaUtil 3.5%). Swizzle spreads lanes to the b128 floor.
template <bool ABF16>
__global__ __launch_bounds__(256) void k_gemm_mfma(
    const void* __restrict__ Asrc, const float* __restrict__ W,
    const float* __restrict__ asrc, const float* __restrict__ adst,
    unsigned char* __restrict__ hq, float* __restrict__ vas, float* __restrict__ vad,
    int nrows)
{
    __shared__ unsigned short Wt[128 * 128];  // swizzled [n][k] bf16, 32 KB
    int tid = threadIdx.x;
    int lane = tid & 63, wv = tid >> 6;
    int row0 = blockIdx.x * 128;
    int c0 = lane & 15, g = lane >> 4;

    // ---- stage Wt = W^T (once), swizzled ----
    {
        int k = tid >> 1;
        int kg = k >> 3, kr = k & 7;
        int n0 = (tid & 1) * 64;
        const float4* wr = (const float4*)&W[k * 128 + n0];
#pragma unroll
        for (int i = 0; i < 16; ++i) {
            float4 v = wr[i];
            int n = n0 + i * 4;
#pragma unroll
            for (int j = 0; j < 4; ++j) {
                int nn = n + j;
                float val = (&v.x)[j];
                Wt[(nn * 16 + (kg ^ (nn & 15))) * 8 + kr] = bf16r(val);
            }
        }
    }
    __syncthreads();

    f32x4 acc[2][8];
#pragma unroll
    for (int mi = 0; mi < 2; ++mi)
#pragma unroll
        for (int ni = 0; ni < 8; ++ni)
#pragma unroll
            for (int q = 0; q < 4; ++q) acc[mi][ni][q] = 0.f;

    int rA[2];
#pragma unroll
    for (int mi = 0; mi < 2; ++mi)
        rA[mi] = min(row0 + wv * 32 + mi * 16 + c0, nrows - 1);

#pragma unroll
    for (int ks = 0; ks < 4; ++ks) {
        int k0 = ks * 32;
        int kgbase = k0 >> 3;
        bf16x8 af[2];
#pragma unroll
        for (int mi = 0; mi < 2; ++mi) {
            if (ABF16) {
                af[mi] = *(const bf16x8*)((const unsigned short*)Asrc + (size_t)rA[mi] * 128 + k0 + g * 8);
            } else {
                const float4* ap = (const float4*)((const float*)Asrc + (size_t)rA[mi] * 128 + k0 + g * 8);
                float4 f0 = ap[0], f1 = ap[1];
                uint4 p = make_uint4(bfpair(f0.x, f0.y), bfpair(f0.z, f0.w),
                                     bfpair(f1.x, f1.y), bfpair(f1.z, f1.w));
                af[mi] = *(bf16x8*)&p;
            }
        }
        bf16x8 bfr[8];
#pragma unroll
        for (int ni = 0; ni < 8; ++ni) {
            int n = ni * 16 + c0;
            bfr[ni] = *(const bf16x8*)&Wt[(n * 16 + ((kgbase + g) ^ c0)) * 8];
        }
#pragma unroll
        for (int mi = 0; mi < 2; ++mi)
#pragma unroll
            for (int ni = 0; ni < 8; ++ni)
                acc[mi][ni] = __builtin_amdgcn_mfma_f32_16x16x32_bf16(bfr[ni], af[mi], acc[mi][ni], 0, 0, 0);
    }

    // ---- epilogue ----
    float4 as4[8], ad4[8];
#pragma unroll
    for (int ni = 0; ni < 8; ++ni) {
        as4[ni] = *(const float4*)&asrc[ni * 16 + g * 4];
        ad4[ni] = *(const float4*)&adst[ni * 16 + g * 4];
    }
#pragma unroll
    for (int mi = 0; mi < 2; ++mi) {
        int node = row0 + wv * 32 + mi * 16 + c0;
        bool ok = node < nrows;
        float s = 0.f, d = 0.f;
        unsigned packs[8];
#pragma unroll
        for (int ni = 0; ni < 8; ++ni) {
            f32x4 vv = acc[mi][ni];
            s = fmaf(vv[0], as4[ni].x, fmaf(vv[1], as4[ni].y, fmaf(vv[2], as4[ni].z, fmaf(vv[3], as4[ni].w, s))));
            d = fmaf(vv[0], ad4[ni].x, fmaf(vv[1], ad4[ni].y, fmaf(vv[2], ad4[ni].z, fmaf(vv[3], ad4[ni].w, d))));
            unsigned p0 = (unsigned)__builtin_amdgcn_cvt_pk_fp8_f32(vv[0], vv[1], 0, false);
            packs[ni] = (unsigned)__builtin_amdgcn_cvt_pk_fp8_f32(vv[2], vv[3], (int)p0, true);
        }
        s += __shfl_xor(s, 16); s += __shfl_xor(s, 32);
        d += __shfl_xor(d, 16); d += __shfl_xor(d, 32);
        if (ok) {
            if (g == 0) { vas[node] = s; vad[node] = d; }
#pragma unroll
            for (int ni = 0; ni < 8; ++ni)
                *(unsigned*)&hq[(size_t)node * 128 + ni * 16 + g * 4] = packs[ni];
        }
    }
}

// ---------------- aggregation: degree-bucketed node order (r21 best-known) ----------------
template <bool RELU>
__global__ __launch_bounds__(256) void k_agg(const unsigned char* __restrict__ hq,
                                             const float* __restrict__ vas,
                                             const float* __restrict__ vad,
                                             const int* __restrict__ row_ptr,
                                             const int* __restrict__ csr,
                                             const int* __restrict__ perm,
                                             const float* __restrict__ bias,
                                             unsigned int* __restrict__ outb,
                                             int n, int chunksPerT) {
    int i = blockIdx.x;
    int slot = i & 7;
    int t = slot >> 1;
    int chunk = ((i >> 3) << 1) | (slot & 1);
    if (chunk >= chunksPerT) return;
    int tid = threadIdx.x;
    int grp = tid >> 4, l = tid & 15;
    int idx = chunk * 16 + grp;
    if (idx >= n) return;
    int w = perm[idx];
    unsigned int tbase = (unsigned int)t * (unsigned int)n;
    unsigned int g = tbase + (unsigned int)w;
    int beg = row_ptr[w], end = row_ptr[w + 1];
    float advl = vad[g];

    f32x2 acc2[4];
#pragma unroll
    for (int q = 0; q < 4; ++q) { acc2[q].x = 0.f; acc2[q].y = 0.f; }
    float zp = 0.f;

    for (int c = beg; c < end; c += 16) {
        int raw = csr[c + l];                       // coalesced
        unsigned int s_l = tbase + (unsigned int)(raw & 0x7fffffff);
        float e = vas[s_l] + advl;
        e = e > 0.f ? e : LEAKY * e;
        float w_l = (raw >= 0) ? __expf(e) : 0.f;   // pads contribute 0
        zp += w_l;

        unsigned int ofs[16]; float wt[16];
#pragma unroll
        for (int q = 0; q < 16; ++q) {
            ofs[q] = __shfl(s_l, q, 16) * 128u + (unsigned int)(l * 8);  // 32-bit byte offset
            wt[q] = __shfl(w_l, q, 16);
        }
        uint2 v[16];
#pragma unroll
        for (int q = 0; q < 16; ++q)
            v[q] = *(const uint2*)&hq[ofs[q]];
#pragma unroll
        for (int q = 0; q < 16; ++q) {
            f32x2 w2; w2.x = wt[q]; w2.y = wt[q];
            acc2[0] = __builtin_elementwise_fma(w2, __builtin_amdgcn_cvt_pk_f32_fp8(v[q].x, false), acc2[0]);
            acc2[1] = __builtin_elementwise_fma(w2, __builtin_amdgcn_cvt_pk_f32_fp8(v[q].x, true),  acc2[1]);
            acc2[2] = __builtin_elementwise_fma(w2, __builtin_amdgcn_cvt_pk_f32_fp8(v[q].y, false), acc2[2]);
            acc2[3] = __builtin_elementwise_fma(w2, __builtin_amdgcn_cvt_pk_f32_fp8(v[q].y, true),  acc2[3]);
        }
    }

    float z = zp;
#pragma unroll
    for (int o = 1; o < 16; o <<= 1) z += __shfl_xor(z, o, 16);
    float inv = 1.0f / z;

    float4 b0 = *(const float4*)&bias[l * 8];
    float4 b1 = *(const float4*)&bias[l * 8 + 4];
    float4 o0 = make_float4(fmaf(acc2[0].x, inv, b0.x), fmaf(acc2[0].y, inv, b0.y),
                            fmaf(acc2[1].x, inv, b0.z), fmaf(acc2[1].y, inv, b0.w));
    float4 o1 = make_float4(fmaf(acc2[2].x, inv, b1.x), fmaf(acc2[2].y, inv, b1.y),
                            fmaf(acc2[3].x, inv, b1.z), fmaf(acc2[3].y, inv, b1.w));
    if (RELU) {
        o0.x = fmaxf(o0.x, 0.f); o0.y = fmaxf(o0.y, 0.f); o0.z = fmaxf(o0.z, 0.f); o0.w = fmaxf(o0.w, 0.f);
        o1.x = fmaxf(o1.x, 0.f); o1.y = fmaxf(o1.y, 0.f); o1.z = fmaxf(o1.z, 0.f); o1.w = fmaxf(o1.w, 0.f);
    }
    uint4 p = make_uint4(bfpair(o0.x, o0.y), bfpair(o0.z, o0.w),
                         bfpair(o1.x, o1.y), bfpair(o1.z, o1.w));
    *(uint4*)&outb[(size_t)g * 64 + l * 4] = p;
}

// ---------------- batch mean pool (batch_idx sorted), bf16 t-major input ----------------
__global__ __launch_bounds__(128) void k_pool(const unsigned int* __restrict__ h,
                                              const int* __restrict__ bstart,
                                              float* __restrict__ out, int n, int T) {
    int b = blockIdx.x;
    int chunk = blockIdx.y;
    int t = blockIdx.z;
    int f = threadIdx.x;
    int s = bstart[b], e = bstart[b + 1];
    int cnt = e - s;
    if (cnt <= 0) return;
    int len = (cnt + 31) / 32;
    int cs = s + chunk * len;
    int ce = min(cs + len, e);
    if (cs >= ce) return;
    const unsigned int* ht = h + (size_t)t * n * 64;
    float acc = 0.f;
    for (int nidx = cs; nidx < ce; ++nidx) {
        unsigned int v = ht[(size_t)nidx * 64 + (f >> 1)];
        acc += __uint_as_float((f & 1) ? (v & 0xffff0000u) : (v << 16));
    }
    atomicAdd(&out[(size_t)(b * T + t) * 128 + f], acc / (float)cnt);
}

// ---------------- launch ----------------

extern "C" void kernel_launch(void* const* d_in, const int* in_sizes, int n_in,
                              void* d_out, int out_size, void* d_ws, size_t ws_size,
                              hipStream_t stream) {
    const float* x    = (const float*)d_in[0];
    const int*   ei   = (const int*)d_in[1];
    const int*   bidx = (const int*)d_in[2];
    const float* W1   = (const float*)d_in[3];
    const float* as1  = (const float*)d_in[4];
    const float* ad1  = (const float*)d_in[5];
    const float* b1   = (const float*)d_in[6];
    const float* W2   = (const float*)d_in[7];
    const float* as2  = (const float*)d_in[8];
    const float* ad2  = (const float*)d_in[9];
    const float* b2   = (const float*)d_in[10];
    float* out = (float*)d_out;

    const int E = in_sizes[1] / 2;
    const int N = in_sizes[2];
    const int T = in_sizes[0] / (N * 128);   // == 4 (swizzle assumes 4)
    const int B = out_size / (T * 128);
    const int* src = ei;
    const int* dst = ei + E;
    const int NT = N * T;

    char* wsp = (char*)d_ws;
    auto alloc = [&](size_t bytes) { void* p = wsp; wsp += (bytes + 255) / 256 * 256; return p; };
    unsigned char* hq    = (unsigned char*)alloc((size_t)NT * 128);    // fp8 GEMM out (gather table)
    unsigned int* hb2    = (unsigned int*)alloc((size_t)NT * 64 * 4);  // bf16 agg out, t-major
    float* vas           = (float*)alloc((size_t)NT * 4);
    float* vad           = (float*)alloc((size_t)NT * 4);
    int* row_ptr         = (int*)alloc((size_t)(N + 1) * 4);
    int* cnt             = (int*)alloc((size_t)N * 4);                 // reused as scatter cursor
    int* csr             = (int*)alloc(((size_t)E + 16ull * N + 64) * 4); // padded CSR
    int* perm            = (int*)alloc((size_t)N * 4);                 // degree-sorted node order
    int* hist            = (int*)alloc(32 * 4);
    int* bcur            = (int*)alloc(32 * 4);
    int* bstart          = (int*)alloc((size_t)(B + 2) * 4);
    int  nScanB          = (N + 255) / 256;
    int* bsum            = (int*)alloc((size_t)nScanB * 4);
    int* boff            = (int*)alloc((size_t)nScanB * 4);

    hipMemsetAsync(d_out, 0, (size_t)out_size * sizeof(float), stream);

    int gN = (N + 255) / 256, gE = (E + 255) / 256;
    k_init<<<gN, 256, 0, stream>>>(cnt, bstart, hist, N, B + 1);
    k_count<<<gE, 256, 0, stream>>>(dst, cnt, E, bidx, bstart, N);
    k_scanA<<<nScanB, 256, 0, stream>>>(cnt, bsum, N);
    k_scanB<<<1, 256, 0, stream>>>(bsum, boff, nScanB, bstart, N, B);
    k_scanC<<<nScanB, 256, 0, stream>>>(cnt, boff, row_ptr, csr, cnt, hist, N);
    k_scatter<<<gE, 256, 0, stream>>>(src, dst, cnt, csr, E);
    k_bscan<<<1, 1, 0, stream>>>(hist, bcur);
    k_pad<<<gN, 256, 0, stream>>>(row_ptr, cnt, csr, bcur, perm, N);

    int gGemm = (NT + 127) / 128;
    int chunksPerT = (N + 15) / 16;
    int chunksPad = ((chunksPerT + 1) / 2) * 2;
    int gAggFlat = chunksPad * 4;                   // T==4
    k_gemm_mfma<false><<<gGemm, 256, 0, stream>>>(x,   W1, as1, ad1, hq, vas, vad, NT);
    k_agg<true ><<<gAggFlat, 256, 0, stream>>>(hq, vas, vad, row_ptr, csr, perm, b1, hb2, N, chunksPerT);
    k_gemm_mfma<true ><<<gGemm, 256, 0, stream>>>(hb2, W2, as2, ad2, hq, vas, vad, NT);
    k_agg<false><<<gAggFlat, 256, 0, stream>>>(hq, vas, vad, row_ptr, csr, perm, b2, hb2, N, chunksPerT);
    k_pool<<<dim3(B, 32, T), 128, 0, stream>>>(hb2, bstart, out, N, T);
}

// Round 23
// 332.161 us; speedup vs baseline: 1.0703x; 1.0703x over previous
//
#include <hip/hip_runtime.h>
#include <hip/hip_bf16.h>

#define LEAKY 0.2f

typedef __attribute__((ext_vector_type(8))) short bf16x8;
typedef __attribute__((ext_vector_type(4))) float f32x4;
typedef __attribute__((ext_vector_type(2))) float f32x2;

// ---------------- CSR build (chunk-16 padded), fused setup ----------------

__global__ __launch_bounds__(256) void k_init(int* cnt, int* bstart, int* hist, int n, int nb) {
    int i = blockIdx.x * 256 + threadIdx.x;
    if (i < n) cnt[i] = 1;            // self-loop pre-counted
    if (i < nb) bstart[i] = n;        // batch-boundary init
    if (i < 32) hist[i] = 0;          // degree-bucket histogram
}

// edge count + batch boundary detection (gE blocks >= gN)
__global__ __launch_bounds__(256) void k_count(const int* __restrict__ dst, int* cnt, int e,
                                               const int* __restrict__ bidx, int* bstart, int n) {
    int i = blockIdx.x * 256 + threadIdx.x;
    if (i < e) atomicAdd(&cnt[dst[i]], 1);
    if (i < n) {
        int b = bidx[i];
        if (i == 0 || bidx[i - 1] != b) atomicMin(&bstart[b], i);
    }
}

// block-wide inclusive scan of one value per thread (256 threads)
__device__ inline int block_incl_scan(int v, int* lds) {
    int lane = threadIdx.x & 63, wid = threadIdx.x >> 6;
    int s = v;
#pragma unroll
    for (int o = 1; o < 64; o <<= 1) { int t = __shfl_up(s, o); if (lane >= o) s += t; }
    if (lane == 63) lds[wid] = s;
    __syncthreads();
    int add = 0;
#pragma unroll
    for (int ww = 0; ww < 3; ++ww) if (ww < wid) add += lds[ww];
    return s + add;
}

__global__ __launch_bounds__(256) void k_scanA(const int* __restrict__ cnt, int* bsum, int n) {
    __shared__ int lds[4];
    int i = blockIdx.x * 256 + threadIdx.x;
    int v = (i < n) ? ((cnt[i] + 15) & ~15) : 0;
    int s = block_incl_scan(v, lds);
    if (threadIdx.x == 255) bsum[blockIdx.x] = s;
}

// scan of block sums + batch-boundary backward fill
__global__ __launch_bounds__(256) void k_scanB(int* bsum, int* boff, int nb,
                                               int* bstart, int n, int nbatch) {
    __shared__ int lds[4];
    int i = threadIdx.x;
    int v = (i < nb) ? bsum[i] : 0;
    int s = block_incl_scan(v, lds);
    if (i < nb) boff[i] = s - v;   // exclusive
    if (i == 0) {
        bstart[nbatch] = n;
        for (int b = nbatch - 1; b >= 0; --b)
            if (bstart[b] == n) bstart[b] = bstart[b + 1];
    }
}

// final scan + self-loop placement + cursor init + degree histogram (LDS-aggregated)
__global__ __launch_bounds__(256) void k_scanC(const int* __restrict__ cnt, const int* __restrict__ boff,
                                               int* row_ptr, int* csr, int* cursor, int* hist, int n) {
    __shared__ int lds[4];
    __shared__ int lh[32];
    int tid = threadIdx.x;
    if (tid < 32) lh[tid] = 0;
    int i = blockIdx.x * 256 + tid;
    int v = (i < n) ? ((cnt[i] + 15) & ~15) : 0;
    int s = block_incl_scan(v, lds) + boff[blockIdx.x];
    __syncthreads();
    if (i < n) {
        int excl = s - v;             // row_ptr[i]
        row_ptr[i + 1] = s;
        csr[excl] = i;                // self-loop first
        cursor[i] = excl + 1;
        atomicAdd(&lh[min(v >> 4, 31)], 1);   // LDS atomic
    }
    if (i == 0) row_ptr[0] = 0;
    __syncthreads();
    if (tid < 32 && lh[tid]) atomicAdd(&hist[tid], lh[tid]);
}

__global__ __launch_bounds__(256) void k_scatter(const int* __restrict__ src, const int* __restrict__ dst,
                                                 int* cursor, int* csr, int e) {
    int i = blockIdx.x * 256 + threadIdx.x;
    if (i < e) { int p = atomicAdd(&cursor[dst[i]], 1); csr[p] = src[i]; }
}

// exclusive scan of the 32-bucket histogram -> bucket cursors
__global__ void k_bscan(const int* __restrict__ hist, int* bcur) {
    int run = 0;
    for (int b = 0; b < 32; ++b) { bcur[b] = run; run += hist[b]; }
}

// pad slots + degree-bucketed permutation via two-level counting sort
__global__ __launch_bounds__(256) void k_pad(const int* __restrict__ row_ptr, const int* __restrict__ cursor,
                                             int* csr, int* bcur, int* perm, int n) {
    __shared__ int lh[32];    // block-local bucket counts
    __shared__ int lbase[32]; // reserved global base per bucket
    int tid = threadIdx.x;
    if (tid < 32) lh[tid] = 0;
    __syncthreads();
    int i = blockIdx.x * 256 + tid;
    int bkt = 0, lpos = 0, b0 = 0, p = 0, e = 0;
    if (i < n) {
        b0 = row_ptr[i]; p = cursor[i]; e = row_ptr[i + 1];
        bkt = min((e - b0) >> 4, 31);
        lpos = atomicAdd(&lh[bkt], 1);        // LDS atomic (fast)
    }
    __syncthreads();
    if (tid < 32 && lh[tid]) lbase[tid] = atomicAdd(&bcur[tid], lh[tid]);
    __syncthreads();
    if (i < n) {
        perm[lbase[bkt] + lpos] = i;
        int v = i | 0x80000000;
        for (; p < e; ++p) csr[p] = v;
    }
}

// round-nearest-even f32 -> bf16 (as ushort)
__device__ inline unsigned short bf16r(float x) {
    unsigned int u = __float_as_uint(x);
    u += 0x7fffu + ((u >> 16) & 1u);
    return (unsigned short)(u >> 16);
}

// round-nearest-even pack of two f32 into one uint (2×bf16, lo|hi<<16)
__device__ inline unsigned int bfpair(float lo, float hi) {
    unsigned int ul = __float_as_uint(lo); ul += 0x7fffu + ((ul >> 16) & 1u);
    unsigned int uh = __float_as_uint(hi); uh += 0x7fffu + ((uh >> 16) & 1u);
    return (ul >> 16) | (uh & 0xffff0000u);
}

// one-time: W[k][n] f32 -> pre-swizzled bf16 W^T global table
// wtg[(n*16 + (kg ^ (n&15)))*8 + kr],  kg=k>>3, kr=k&7  (matches GEMM read formula)
__global__ __launch_bounds__(256) void k_prep(const float* __restrict__ W, unsigned short* __restrict__ wtg) {
    int idx = blockIdx.x * 256 + threadIdx.x;   // 0..16383
    int k = idx >> 7, n = idx & 127;
    int kg = k >> 3, kr = k & 7;
    wtg[(n * 16 + (kg ^ (n & 15))) * 8 + kr] = bf16r(W[k * 128 + n]);
}

// ---------------- MFMA GEMM + attention logits (batched over all T snapshots) ----------------
// OPERAND-SWAPPED: D = mfma(W_frag, X_frag). Wt staged by LINEAR vectorized copy from the
// pre-swizzled global table (r22's in-kernel transpose-scatter = 64 scalar ds_write_b16
// per thread was the GEMM's dominant cost: MfmaUtil 3.5%, all pipes idle).
template <bool ABF16>
__global__ __launch_bounds__(256) void k_gemm_mfma(
    const void* __restrict__ Asrc, const unsigned short* __restrict__ wtg,
    const float* __restrict__ asrc, const float* __restrict__ adst,
    unsigned char* __restrict__ hq, float* __restrict__ vas, float* __restrict__ vad,
    int nrows)
{
    __shared__ unsigned short Wt[128 * 128];  // swizzled [n][k] bf16, 32 KB
    int tid = threadIdx.x;
    int lane = tid & 63, wv = tid >> 6;
    int row0 = blockIdx.x * 128;
    int c0 = lane & 15, g = lane >> 4;

    // ---- stage Wt: linear 32 KB copy (8 x b128 per thread, conflict-free) ----
    {
        const uint4* s4 = (const uint4*)wtg;
        uint4* d4 = (uint4*)Wt;
#pragma unroll
        for (int i = 0; i < 8; ++i)
            d4[tid + i * 256] = s4[tid + i * 256];
    }
    __syncthreads();

    f32x4 acc[2][8];
#pragma unroll
    for (int mi = 0; mi < 2; ++mi)
#pragma unroll
        for (int ni = 0; ni < 8; ++ni)
#pragma unroll
            for (int q = 0; q < 4; ++q) acc[mi][ni][q] = 0.f;

    int rA[2];
#pragma unroll
    for (int mi = 0; mi < 2; ++mi)
        rA[mi] = min(row0 + wv * 32 + mi * 16 + c0, nrows - 1);

#pragma unroll
    for (int ks = 0; ks < 4; ++ks) {
        int k0 = ks * 32;
        int kgbase = k0 >> 3;
        bf16x8 af[2];
#pragma unroll
        for (int mi = 0; mi < 2; ++mi) {
            if (ABF16) {
                af[mi] = *(const bf16x8*)((const unsigned short*)Asrc + (size_t)rA[mi] * 128 + k0 + g * 8);
            } else {
                const float4* ap = (const float4*)((const float*)Asrc + (size_t)rA[mi] * 128 + k0 + g * 8);
                float4 f0 = ap[0], f1 = ap[1];
                uint4 p = make_uint4(bfpair(f0.x, f0.y), bfpair(f0.z, f0.w),
                                     bfpair(f1.x, f1.y), bfpair(f1.z, f1.w));
                af[mi] = *(bf16x8*)&p;
            }
        }
        bf16x8 bfr[8];
#pragma unroll
        for (int ni = 0; ni < 8; ++ni) {
            int n = ni * 16 + c0;
            bfr[ni] = *(const bf16x8*)&Wt[(n * 16 + ((kgbase + g) ^ c0)) * 8];
        }
#pragma unroll
        for (int mi = 0; mi < 2; ++mi)
#pragma unroll
            for (int ni = 0; ni < 8; ++ni)
                acc[mi][ni] = __builtin_amdgcn_mfma_f32_16x16x32_bf16(bfr[ni], af[mi], acc[mi][ni], 0, 0, 0);
    }

    // ---- epilogue ----
    float4 as4[8], ad4[8];
#pragma unroll
    for (int ni = 0; ni < 8; ++ni) {
        as4[ni] = *(const float4*)&asrc[ni * 16 + g * 4];
        ad4[ni] = *(const float4*)&adst[ni * 16 + g * 4];
    }
#pragma unroll
    for (int mi = 0; mi < 2; ++mi) {
        int node = row0 + wv * 32 + mi * 16 + c0;
        bool ok = node < nrows;
        float s = 0.f, d = 0.f;
        unsigned packs[8];
#pragma unroll
        for (int ni = 0; ni < 8; ++ni) {
            f32x4 vv = acc[mi][ni];
            s = fmaf(vv[0], as4[ni].x, fmaf(vv[1], as4[ni].y, fmaf(vv[2], as4[ni].z, fmaf(vv[3], as4[ni].w, s))));
            d = fmaf(vv[0], ad4[ni].x, fmaf(vv[1], ad4[ni].y, fmaf(vv[2], ad4[ni].z, fmaf(vv[3], ad4[ni].w, d))));
            unsigned p0 = (unsigned)__builtin_amdgcn_cvt_pk_fp8_f32(vv[0], vv[1], 0, false);
            packs[ni] = (unsigned)__builtin_amdgcn_cvt_pk_fp8_f32(vv[2], vv[3], (int)p0, true);
        }
        s += __shfl_xor(s, 16); s += __shfl_xor(s, 32);
        d += __shfl_xor(d, 16); d += __shfl_xor(d, 32);
        if (ok) {
            if (g == 0) { vas[node] = s; vad[node] = d; }
#pragma unroll
            for (int ni = 0; ni < 8; ++ni)
                *(unsigned*)&hq[(size_t)node * 128 + ni * 16 + g * 4] = packs[ni];
        }
    }
}

// ---------------- aggregation: degree-bucketed node order (r21 best-known) ----------------
template <bool RELU>
__global__ __launch_bounds__(256) void k_agg(const unsigned char* __restrict__ hq,
                                             const float* __restrict__ vas,
                                             const float* __restrict__ vad,
                                             const int* __restrict__ row_ptr,
                                             const int* __restrict__ csr,
                                             const int* __restrict__ perm,
                                             const float* __restrict__ bias,
                                             unsigned int* __restrict__ outb,
                                             int n, int chunksPerT) {
    int i = blockIdx.x;
    int slot = i & 7;
    int t = slot >> 1;
    int chunk = ((i >> 3) << 1) | (slot & 1);
    if (chunk >= chunksPerT) return;
    int tid = threadIdx.x;
    int grp = tid >> 4, l = tid & 15;
    int idx = chunk * 16 + grp;
    if (idx >= n) return;
    int w = perm[idx];
    unsigned int tbase = (unsigned int)t * (unsigned int)n;
    unsigned int g = tbase + (unsigned int)w;
    int beg = row_ptr[w], end = row_ptr[w + 1];
    float advl = vad[g];

    f32x2 acc2[4];
#pragma unroll
    for (int q = 0; q < 4; ++q) { acc2[q].x = 0.f; acc2[q].y = 0.f; }
    float zp = 0.f;

    for (int c = beg; c < end; c += 16) {
        int raw = csr[c + l];                       // coalesced
        unsigned int s_l = tbase + (unsigned int)(raw & 0x7fffffff);
        float e = vas[s_l] + advl;
        e = e > 0.f ? e : LEAKY * e;
        float w_l = (raw >= 0) ? __expf(e) : 0.f;   // pads contribute 0
        zp += w_l;

        unsigned int ofs[16]; float wt[16];
#pragma unroll
        for (int q = 0; q < 16; ++q) {
            ofs[q] = __shfl(s_l, q, 16) * 128u + (unsigned int)(l * 8);  // 32-bit byte offset
            wt[q] = __shfl(w_l, q, 16);
        }
        uint2 v[16];
#pragma unroll
        for (int q = 0; q < 16; ++q)
            v[q] = *(const uint2*)&hq[ofs[q]];
#pragma unroll
        for (int q = 0; q < 16; ++q) {
            f32x2 w2; w2.x = wt[q]; w2.y = wt[q];
            acc2[0] = __builtin_elementwise_fma(w2, __builtin_amdgcn_cvt_pk_f32_fp8(v[q].x, false), acc2[0]);
            acc2[1] = __builtin_elementwise_fma(w2, __builtin_amdgcn_cvt_pk_f32_fp8(v[q].x, true),  acc2[1]);
            acc2[2] = __builtin_elementwise_fma(w2, __builtin_amdgcn_cvt_pk_f32_fp8(v[q].y, false), acc2[2]);
            acc2[3] = __builtin_elementwise_fma(w2, __builtin_amdgcn_cvt_pk_f32_fp8(v[q].y, true),  acc2[3]);
        }
    }

    float z = zp;
#pragma unroll
    for (int o = 1; o < 16; o <<= 1) z += __shfl_xor(z, o, 16);
    float inv = 1.0f / z;

    float4 b0 = *(const float4*)&bias[l * 8];
    float4 b1 = *(const float4*)&bias[l * 8 + 4];
    float4 o0 = make_float4(fmaf(acc2[0].x, inv, b0.x), fmaf(acc2[0].y, inv, b0.y),
                            fmaf(acc2[1].x, inv, b0.z), fmaf(acc2[1].y, inv, b0.w));
    float4 o1 = make_float4(fmaf(acc2[2].x, inv, b1.x), fmaf(acc2[2].y, inv, b1.y),
                            fmaf(acc2[3].x, inv, b1.z), fmaf(acc2[3].y, inv, b1.w));
    if (RELU) {
        o0.x = fmaxf(o0.x, 0.f); o0.y = fmaxf(o0.y, 0.f); o0.z = fmaxf(o0.z, 0.f); o0.w = fmaxf(o0.w, 0.f);
        o1.x = fmaxf(o1.x, 0.f); o1.y = fmaxf(o1.y, 0.f); o1.z = fmaxf(o1.z, 0.f); o1.w = fmaxf(o1.w, 0.f);
    }
    uint4 p = make_uint4(bfpair(o0.x, o0.y), bfpair(o0.z, o0.w),
                         bfpair(o1.x, o1.y), bfpair(o1.z, o1.w));
    *(uint4*)&outb[(size_t)g * 64 + l * 4] = p;
}

// ---------------- batch mean pool (batch_idx sorted), bf16 t-major input ----------------
__global__ __launch_bounds__(128) void k_pool(const unsigned int* __restrict__ h,
                                              const int* __restrict__ bstart,
                                              float* __restrict__ out, int n, int T) {
    int b = blockIdx.x;
    int chunk = blockIdx.y;
    int t = blockIdx.z;
    int f = threadIdx.x;
    int s = bstart[b], e = bstart[b + 1];
    int cnt = e - s;
    if (cnt <= 0) return;
    int len = (cnt + 31) / 32;
    int cs = s + chunk * len;
    int ce = min(cs + len, e);
    if (cs >= ce) return;
    const unsigned int* ht = h + (size_t)t * n * 64;
    float acc = 0.f;
    for (int nidx = cs; nidx < ce; ++nidx) {
        unsigned int v = ht[(size_t)nidx * 64 + (f >> 1)];
        acc += __uint_as_float((f & 1) ? (v & 0xffff0000u) : (v << 16));
    }
    atomicAdd(&out[(size_t)(b * T + t) * 128 + f], acc / (float)cnt);
}

// ---------------- launch ----------------

extern "C" void kernel_launch(void* const* d_in, const int* in_sizes, int n_in,
                              void* d_out, int out_size, void* d_ws, size_t ws_size,
                              hipStream_t stream) {
    const float* x    = (const float*)d_in[0];
    const int*   ei   = (const int*)d_in[1];
    const int*   bidx = (const int*)d_in[2];
    const float* W1   = (const float*)d_in[3];
    const float* as1  = (const float*)d_in[4];
    const float* ad1  = (const float*)d_in[5];
    const float* b1   = (const float*)d_in[6];
    const float* W2   = (const float*)d_in[7];
    const float* as2  = (const float*)d_in[8];
    const float* ad2  = (const float*)d_in[9];
    const float* b2   = (const float*)d_in[10];
    float* out = (float*)d_out;

    const int E = in_sizes[1] / 2;
    const int N = in_sizes[2];
    const int T = in_sizes[0] / (N * 128);   // == 4 (swizzle assumes 4)
    const int B = out_size / (T * 128);
    const int* src = ei;
    const int* dst = ei + E;
    const int NT = N * T;

    char* wsp = (char*)d_ws;
    auto alloc = [&](size_t bytes) { void* p = wsp; wsp += (bytes + 255) / 256 * 256; return p; };
    unsigned char* hq    = (unsigned char*)alloc((size_t)NT * 128);    // fp8 GEMM out (gather table)
    unsigned int* hb2    = (unsigned int*)alloc((size_t)NT * 64 * 4);  // bf16 agg out, t-major
    float* vas           = (float*)alloc((size_t)NT * 4);
    float* vad           = (float*)alloc((size_t)NT * 4);
    unsigned short* wt1g = (unsigned short*)alloc(128 * 128 * 2);      // pre-swizzled bf16 W1^T
    unsigned short* wt2g = (unsigned short*)alloc(128 * 128 * 2);      // pre-swizzled bf16 W2^T
    int* row_ptr         = (int*)alloc((size_t)(N + 1) * 4);
    int* cnt             = (int*)alloc((size_t)N * 4);                 // reused as scatter cursor
    int* csr             = (int*)alloc(((size_t)E + 16ull * N + 64) * 4); // padded CSR
    int* perm            = (int*)alloc((size_t)N * 4);                 // degree-sorted node order
    int* hist            = (int*)alloc(32 * 4);
    int* bcur            = (int*)alloc(32 * 4);
    int* bstart          = (int*)alloc((size_t)(B + 2) * 4);
    int  nScanB          = (N + 255) / 256;
    int* bsum            = (int*)alloc((size_t)nScanB * 4);
    int* boff            = (int*)alloc((size_t)nScanB * 4);

    hipMemsetAsync(d_out, 0, (size_t)out_size * sizeof(float), stream);

    int gN = (N + 255) / 256, gE = (E + 255) / 256;
    k_init<<<gN, 256, 0, stream>>>(cnt, bstart, hist, N, B + 1);
    k_count<<<gE, 256, 0, stream>>>(dst, cnt, E, bidx, bstart, N);
    k_prep<<<64, 256, 0, stream>>>(W1, wt1g);
    k_prep<<<64, 256, 0, stream>>>(W2, wt2g);
    k_scanA<<<nScanB, 256, 0, stream>>>(cnt, bsum, N);
    k_scanB<<<1, 256, 0, stream>>>(bsum, boff, nScanB, bstart, N, B);
    k_scanC<<<nScanB, 256, 0, stream>>>(cnt, boff, row_ptr, csr, cnt, hist, N);
    k_scatter<<<gE, 256, 0, stream>>>(src, dst, cnt, csr, E);
    k_bscan<<<1, 1, 0, stream>>>(hist, bcur);
    k_pad<<<gN, 256, 0, stream>>>(row_ptr, cnt, csr, bcur, perm, N);

    int gGemm = (NT + 127) / 128;
    int chunksPerT = (N + 15) / 16;
    int chunksPad = ((chunksPerT + 1) / 2) * 2;
    int gAggFlat = chunksPad * 4;                   // T==4
    k_gemm_mfma<false><<<gGemm, 256, 0, stream>>>(x,   wt1g, as1, ad1, hq, vas, vad, NT);
    k_agg<true ><<<gAggFlat, 256, 0, stream>>>(hq, vas, vad, row_ptr, csr, perm, b1, hb2, N, chunksPerT);
    k_gemm_mfma<true ><<<gGemm, 256, 0, stream>>>(hb2, wt2g, as2, ad2, hq, vas, vad, NT);
    k_agg<false><<<gAggFlat, 256, 0, stream>>>(hq, vas, vad, row_ptr, csr, perm, b2, hb2, N, chunksPerT);
    k_pool<<<dim3(B, 32, T), 128, 0, stream>>>(hb2, bstart, out, N, T);
}

// Round 24
// 328.189 us; speedup vs baseline: 1.0833x; 1.0121x over previous
//
#include <hip/hip_runtime.h>
#include <hip/hip_bf16.h>

#define LEAKY 0.2f

typedef __attribute__((ext_vector_type(8))) short bf16x8;
typedef __attribute__((ext_vector_type(4))) float f32x4;
typedef __attribute__((ext_vector_type(2))) float f32x2;

// ---------------- CSR build (chunk-8 padded), fused setup ----------------

__global__ __launch_bounds__(256) void k_init(int* cnt, int* bstart, int* hist, int n, int nb) {
    int i = blockIdx.x * 256 + threadIdx.x;
    if (i < n) cnt[i] = 1;            // self-loop pre-counted
    if (i < nb) bstart[i] = n;        // batch-boundary init
    if (i < 32) hist[i] = 0;          // degree-bucket histogram
}

// edge count + batch boundary detection (gE blocks >= gN)
__global__ __launch_bounds__(256) void k_count(const int* __restrict__ dst, int* cnt, int e,
                                               const int* __restrict__ bidx, int* bstart, int n) {
    int i = blockIdx.x * 256 + threadIdx.x;
    if (i < e) atomicAdd(&cnt[dst[i]], 1);
    if (i < n) {
        int b = bidx[i];
        if (i == 0 || bidx[i - 1] != b) atomicMin(&bstart[b], i);
    }
}

// block-wide inclusive scan of one value per thread (256 threads)
__device__ inline int block_incl_scan(int v, int* lds) {
    int lane = threadIdx.x & 63, wid = threadIdx.x >> 6;
    int s = v;
#pragma unroll
    for (int o = 1; o < 64; o <<= 1) { int t = __shfl_up(s, o); if (lane >= o) s += t; }
    if (lane == 63) lds[wid] = s;
    __syncthreads();
    int add = 0;
#pragma unroll
    for (int ww = 0; ww < 3; ++ww) if (ww < wid) add += lds[ww];
    return s + add;
}

__global__ __launch_bounds__(256) void k_scanA(const int* __restrict__ cnt, int* bsum, int n) {
    __shared__ int lds[4];
    int i = blockIdx.x * 256 + threadIdx.x;
    int v = (i < n) ? ((cnt[i] + 7) & ~7) : 0;
    int s = block_incl_scan(v, lds);
    if (threadIdx.x == 255) bsum[blockIdx.x] = s;
}

// scan of block sums + batch-boundary backward fill
__global__ __launch_bounds__(256) void k_scanB(int* bsum, int* boff, int nb,
                                               int* bstart, int n, int nbatch) {
    __shared__ int lds[4];
    int i = threadIdx.x;
    int v = (i < nb) ? bsum[i] : 0;
    int s = block_incl_scan(v, lds);
    if (i < nb) boff[i] = s - v;   // exclusive
    if (i == 0) {
        bstart[nbatch] = n;
        for (int b = nbatch - 1; b >= 0; --b)
            if (bstart[b] == n) bstart[b] = bstart[b + 1];
    }
}

// final scan + self-loop placement + cursor init + chunk-count histogram (LDS-aggregated)
__global__ __launch_bounds__(256) void k_scanC(const int* __restrict__ cnt, const int* __restrict__ boff,
                                               int* row_ptr, int* csr, int* cursor, int* hist, int n) {
    __shared__ int lds[4];
    __shared__ int lh[32];
    int tid = threadIdx.x;
    if (tid < 32) lh[tid] = 0;
    int i = blockIdx.x * 256 + tid;
    int v = (i < n) ? ((cnt[i] + 7) & ~7) : 0;
    int s = block_incl_scan(v, lds) + boff[blockIdx.x];
    __syncthreads();
    if (i < n) {
        int excl = s - v;             // row_ptr[i]
        row_ptr[i + 1] = s;
        csr[excl] = i;                // self-loop first
        cursor[i] = excl + 1;
        atomicAdd(&lh[min(v >> 3, 31)], 1);   // LDS atomic (8-chunk count)
    }
    if (i == 0) row_ptr[0] = 0;
    __syncthreads();
    if (tid < 32 && lh[tid]) atomicAdd(&hist[tid], lh[tid]);
}

__global__ __launch_bounds__(256) void k_scatter(const int* __restrict__ src, const int* __restrict__ dst,
                                                 int* cursor, int* csr, int e) {
    int i = blockIdx.x * 256 + threadIdx.x;
    if (i < e) { int p = atomicAdd(&cursor[dst[i]], 1); csr[p] = src[i]; }
}

// exclusive scan of the 32-bucket histogram -> bucket cursors
__global__ void k_bscan(const int* __restrict__ hist, int* bcur) {
    int run = 0;
    for (int b = 0; b < 32; ++b) { bcur[b] = run; run += hist[b]; }
}

// pad slots + degree-bucketed permutation via two-level counting sort
__global__ __launch_bounds__(256) void k_pad(const int* __restrict__ row_ptr, const int* __restrict__ cursor,
                                             int* csr, int* bcur, int* perm, int n) {
    __shared__ int lh[32];    // block-local bucket counts
    __shared__ int lbase[32]; // reserved global base per bucket
    int tid = threadIdx.x;
    if (tid < 32) lh[tid] = 0;
    __syncthreads();
    int i = blockIdx.x * 256 + tid;
    int bkt = 0, lpos = 0, b0 = 0, p = 0, e = 0;
    if (i < n) {
        b0 = row_ptr[i]; p = cursor[i]; e = row_ptr[i + 1];
        bkt = min((e - b0) >> 3, 31);
        lpos = atomicAdd(&lh[bkt], 1);        // LDS atomic (fast)
    }
    __syncthreads();
    if (tid < 32 && lh[tid]) lbase[tid] = atomicAdd(&bcur[tid], lh[tid]);
    __syncthreads();
    if (i < n) {
        perm[lbase[bkt] + lpos] = i;
        int v = i | 0x80000000;
        for (; p < e; ++p) csr[p] = v;
    }
}

// round-nearest-even f32 -> bf16 (as ushort)
__device__ inline unsigned short bf16r(float x) {
    unsigned int u = __float_as_uint(x);
    u += 0x7fffu + ((u >> 16) & 1u);
    return (unsigned short)(u >> 16);
}

// round-nearest-even pack of two f32 into one uint (2×bf16, lo|hi<<16)
__device__ inline unsigned int bfpair(float lo, float hi) {
    unsigned int ul = __float_as_uint(lo); ul += 0x7fffu + ((ul >> 16) & 1u);
    unsigned int uh = __float_as_uint(hi); uh += 0x7fffu + ((uh >> 16) & 1u);
    return (ul >> 16) | (uh & 0xffff0000u);
}

// one-time: W[k][n] f32 -> pre-swizzled bf16 W^T global table
// wtg[(n*16 + (kg ^ (n&15)))*8 + kr],  kg=k>>3, kr=k&7  (matches GEMM read formula)
__global__ __launch_bounds__(256) void k_prep(const float* __restrict__ W, unsigned short* __restrict__ wtg) {
    int idx = blockIdx.x * 256 + threadIdx.x;   // 0..16383
    int k = idx >> 7, n = idx & 127;
    int kg = k >> 3, kr = k & 7;
    wtg[(n * 16 + (kg ^ (n & 15))) * 8 + kr] = bf16r(W[k * 128 + n]);
}

// ---------------- MFMA GEMM + attention logits (batched over all T snapshots) ----------------
// OPERAND-SWAPPED: D = mfma(W_frag, X_frag). Wt staged by LINEAR vectorized copy from the
// pre-swizzled global table.
template <bool ABF16>
__global__ __launch_bounds__(256) void k_gemm_mfma(
    const void* __restrict__ Asrc, const unsigned short* __restrict__ wtg,
    const float* __restrict__ asrc, const float* __restrict__ adst,
    unsigned char* __restrict__ hq, float* __restrict__ vas, float* __restrict__ vad,
    int nrows)
{
    __shared__ unsigned short Wt[128 * 128];  // swizzled [n][k] bf16, 32 KB
    int tid = threadIdx.x;
    int lane = tid & 63, wv = tid >> 6;
    int row0 = blockIdx.x * 128;
    int c0 = lane & 15, g = lane >> 4;

    // ---- stage Wt: linear 32 KB copy (8 x b128 per thread, conflict-free) ----
    {
        const uint4* s4 = (const uint4*)wtg;
        uint4* d4 = (uint4*)Wt;
#pragma unroll
        for (int i = 0; i < 8; ++i)
            d4[tid + i * 256] = s4[tid + i * 256];
    }
    __syncthreads();

    f32x4 acc[2][8];
#pragma unroll
    for (int mi = 0; mi < 2; ++mi)
#pragma unroll
        for (int ni = 0; ni < 8; ++ni)
#pragma unroll
            for (int q = 0; q < 4; ++q) acc[mi][ni][q] = 0.f;

    int rA[2];
#pragma unroll
    for (int mi = 0; mi < 2; ++mi)
        rA[mi] = min(row0 + wv * 32 + mi * 16 + c0, nrows - 1);

#pragma unroll
    for (int ks = 0; ks < 4; ++ks) {
        int k0 = ks * 32;
        int kgbase = k0 >> 3;
        bf16x8 af[2];
#pragma unroll
        for (int mi = 0; mi < 2; ++mi) {
            if (ABF16) {
                af[mi] = *(const bf16x8*)((const unsigned short*)Asrc + (size_t)rA[mi] * 128 + k0 + g * 8);
            } else {
                const float4* ap = (const float4*)((const float*)Asrc + (size_t)rA[mi] * 128 + k0 + g * 8);
                float4 f0 = ap[0], f1 = ap[1];
                uint4 p = make_uint4(bfpair(f0.x, f0.y), bfpair(f0.z, f0.w),
                                     bfpair(f1.x, f1.y), bfpair(f1.z, f1.w));
                af[mi] = *(bf16x8*)&p;
            }
        }
        bf16x8 bfr[8];
#pragma unroll
        for (int ni = 0; ni < 8; ++ni) {
            int n = ni * 16 + c0;
            bfr[ni] = *(const bf16x8*)&Wt[(n * 16 + ((kgbase + g) ^ c0)) * 8];
        }
#pragma unroll
        for (int mi = 0; mi < 2; ++mi)
#pragma unroll
            for (int ni = 0; ni < 8; ++ni)
                acc[mi][ni] = __builtin_amdgcn_mfma_f32_16x16x32_bf16(bfr[ni], af[mi], acc[mi][ni], 0, 0, 0);
    }

    // ---- epilogue ----
    float4 as4[8], ad4[8];
#pragma unroll
    for (int ni = 0; ni < 8; ++ni) {
        as4[ni] = *(const float4*)&asrc[ni * 16 + g * 4];
        ad4[ni] = *(const float4*)&adst[ni * 16 + g * 4];
    }
#pragma unroll
    for (int mi = 0; mi < 2; ++mi) {
        int node = row0 + wv * 32 + mi * 16 + c0;
        bool ok = node < nrows;
        float s = 0.f, d = 0.f;
        unsigned packs[8];
#pragma unroll
        for (int ni = 0; ni < 8; ++ni) {
            f32x4 vv = acc[mi][ni];
            s = fmaf(vv[0], as4[ni].x, fmaf(vv[1], as4[ni].y, fmaf(vv[2], as4[ni].z, fmaf(vv[3], as4[ni].w, s))));
            d = fmaf(vv[0], ad4[ni].x, fmaf(vv[1], ad4[ni].y, fmaf(vv[2], ad4[ni].z, fmaf(vv[3], ad4[ni].w, d))));
            unsigned p0 = (unsigned)__builtin_amdgcn_cvt_pk_fp8_f32(vv[0], vv[1], 0, false);
            packs[ni] = (unsigned)__builtin_amdgcn_cvt_pk_fp8_f32(vv[2], vv[3], (int)p0, true);
        }
        s += __shfl_xor(s, 16); s += __shfl_xor(s, 32);
        d += __shfl_xor(d, 16); d += __shfl_xor(d, 32);
        if (ok) {
            if (g == 0) { vas[node] = s; vad[node] = d; }
#pragma unroll
            for (int ni = 0; ni < 8; ++ni)
                *(unsigned*)&hq[(size_t)node * 128 + ni * 16 + g * 4] = packs[ni];
        }
    }
}

// ---------------- aggregation: 8-lane group per dst node, chunk-8, degree-bucketed ----------------
// Lane loads uint4 (16 fp8 feats) per edge -> half the VMEM instrs/byte vs uint2; padding
// waste 24.6->~21 slots/node (-13% gathered bytes). Width-8 shfl broadcast; 3-step z-reduce.
template <bool RELU>
__global__ __launch_bounds__(256) void k_agg(const unsigned char* __restrict__ hq,
                                             const float* __restrict__ vas,
                                             const float* __restrict__ vad,
                                             const int* __restrict__ row_ptr,
                                             const int* __restrict__ csr,
                                             const int* __restrict__ perm,
                                             const float* __restrict__ bias,
                                             unsigned int* __restrict__ outb,
                                             int n, int chunksPerT) {
    int i = blockIdx.x;
    int slot = i & 7;
    int t = slot >> 1;
    int chunk = ((i >> 3) << 1) | (slot & 1);
    if (chunk >= chunksPerT) return;
    int tid = threadIdx.x;
    int grp = tid >> 3, l = tid & 7;     // 32 groups of 8 lanes
    int idx = chunk * 32 + grp;
    if (idx >= n) return;
    int w = perm[idx];
    unsigned int tbase = (unsigned int)t * (unsigned int)n;
    unsigned int g = tbase + (unsigned int)w;
    int beg = row_ptr[w], end = row_ptr[w + 1];
    float advl = vad[g];

    f32x2 acc2[8];
#pragma unroll
    for (int q = 0; q < 8; ++q) { acc2[q].x = 0.f; acc2[q].y = 0.f; }
    float zp = 0.f;

    for (int c = beg; c < end; c += 8) {
        int raw = csr[c + l];                       // coalesced (8 consecutive)
        unsigned int s_l = tbase + (unsigned int)(raw & 0x7fffffff);
        float e = vas[s_l] + advl;
        e = e > 0.f ? e : LEAKY * e;
        float w_l = (raw >= 0) ? __expf(e) : 0.f;   // pads contribute 0
        zp += w_l;

        unsigned int ofs[8]; float wt[8];
#pragma unroll
        for (int q = 0; q < 8; ++q) {
            ofs[q] = __shfl(s_l, q, 8) * 128u + (unsigned int)(l * 16);  // 32-bit byte offset
            wt[q] = __shfl(w_l, q, 8);
        }
        uint4 v[8];
#pragma unroll
        for (int q = 0; q < 8; ++q)
            v[q] = *(const uint4*)&hq[ofs[q]];
#pragma unroll
        for (int q = 0; q < 8; ++q) {
            f32x2 w2; w2.x = wt[q]; w2.y = wt[q];
            acc2[0] = __builtin_elementwise_fma(w2, __builtin_amdgcn_cvt_pk_f32_fp8(v[q].x, false), acc2[0]);
            acc2[1] = __builtin_elementwise_fma(w2, __builtin_amdgcn_cvt_pk_f32_fp8(v[q].x, true),  acc2[1]);
            acc2[2] = __builtin_elementwise_fma(w2, __builtin_amdgcn_cvt_pk_f32_fp8(v[q].y, false), acc2[2]);
            acc2[3] = __builtin_elementwise_fma(w2, __builtin_amdgcn_cvt_pk_f32_fp8(v[q].y, true),  acc2[3]);
            acc2[4] = __builtin_elementwise_fma(w2, __builtin_amdgcn_cvt_pk_f32_fp8(v[q].z, false), acc2[4]);
            acc2[5] = __builtin_elementwise_fma(w2, __builtin_amdgcn_cvt_pk_f32_fp8(v[q].z, true),  acc2[5]);
            acc2[6] = __builtin_elementwise_fma(w2, __builtin_amdgcn_cvt_pk_f32_fp8(v[q].w, false), acc2[6]);
            acc2[7] = __builtin_elementwise_fma(w2, __builtin_amdgcn_cvt_pk_f32_fp8(v[q].w, true),  acc2[7]);
        }
    }

    float z = zp;
    z += __shfl_xor(z, 1, 8);
    z += __shfl_xor(z, 2, 8);
    z += __shfl_xor(z, 4, 8);
    float inv = 1.0f / z;

    const float4* bias4 = (const float4*)&bias[l * 16];
    unsigned u[8];
#pragma unroll
    for (int j = 0; j < 4; ++j) {
        float4 bb = bias4[j];
        float o0 = fmaf(acc2[2 * j].x, inv, bb.x);
        float o1 = fmaf(acc2[2 * j].y, inv, bb.y);
        float o2 = fmaf(acc2[2 * j + 1].x, inv, bb.z);
        float o3 = fmaf(acc2[2 * j + 1].y, inv, bb.w);
        if (RELU) {
            o0 = fmaxf(o0, 0.f); o1 = fmaxf(o1, 0.f); o2 = fmaxf(o2, 0.f); o3 = fmaxf(o3, 0.f);
        }
        u[2 * j]     = bfpair(o0, o1);
        u[2 * j + 1] = bfpair(o2, o3);
    }
    *(uint4*)&outb[(size_t)g * 64 + l * 8]     = make_uint4(u[0], u[1], u[2], u[3]);
    *(uint4*)&outb[(size_t)g * 64 + l * 8 + 4] = make_uint4(u[4], u[5], u[6], u[7]);
}

// ---------------- batch mean pool (batch_idx sorted), bf16 t-major input ----------------
__global__ __launch_bounds__(128) void k_pool(const unsigned int* __restrict__ h,
                                              const int* __restrict__ bstart,
                                              float* __restrict__ out, int n, int T) {
    int b = blockIdx.x;
    int chunk = blockIdx.y;
    int t = blockIdx.z;
    int f = threadIdx.x;
    int s = bstart[b], e = bstart[b + 1];
    int cnt = e - s;
    if (cnt <= 0) return;
    int len = (cnt + 31) / 32;
    int cs = s + chunk * len;
    int ce = min(cs + len, e);
    if (cs >= ce) return;
    const unsigned int* ht = h + (size_t)t * n * 64;
    float acc = 0.f;
    for (int nidx = cs; nidx < ce; ++nidx) {
        unsigned int v = ht[(size_t)nidx * 64 + (f >> 1)];
        acc += __uint_as_float((f & 1) ? (v & 0xffff0000u) : (v << 16));
    }
    atomicAdd(&out[(size_t)(b * T + t) * 128 + f], acc / (float)cnt);
}

// ---------------- launch ----------------

extern "C" void kernel_launch(void* const* d_in, const int* in_sizes, int n_in,
                              void* d_out, int out_size, void* d_ws, size_t ws_size,
                              hipStream_t stream) {
    const float* x    = (const float*)d_in[0];
    const int*   ei   = (const int*)d_in[1];
    const int*   bidx = (const int*)d_in[2];
    const float* W1   = (const float*)d_in[3];
    const float* as1  = (const float*)d_in[4];
    const float* ad1  = (const float*)d_in[5];
    const float* b1   = (const float*)d_in[6];
    const float* W2   = (const float*)d_in[7];
    const float* as2  = (const float*)d_in[8];
    const float* ad2  = (const float*)d_in[9];
    const float* b2   = (const float*)d_in[10];
    float* out = (float*)d_out;

    const int E = in_sizes[1] / 2;
    const int N = in_sizes[2];
    const int T = in_sizes[0] / (N * 128);   // == 4 (swizzle assumes 4)
    const int B = out_size / (T * 128);
    const int* src = ei;
    const int* dst = ei + E;
    const int NT = N * T;

    char* wsp = (char*)d_ws;
    auto alloc = [&](size_t bytes) { void* p = wsp; wsp += (bytes + 255) / 256 * 256; return p; };
    unsigned char* hq    = (unsigned char*)alloc((size_t)NT * 128);    // fp8 GEMM out (gather table)
    unsigned int* hb2    = (unsigned int*)alloc((size_t)NT * 64 * 4);  // bf16 agg out, t-major
    float* vas           = (float*)alloc((size_t)NT * 4);
    float* vad           = (float*)alloc((size_t)NT * 4);
    unsigned short* wt1g = (unsigned short*)alloc(128 * 128 * 2);      // pre-swizzled bf16 W1^T
    unsigned short* wt2g = (unsigned short*)alloc(128 * 128 * 2);      // pre-swizzled bf16 W2^T
    int* row_ptr         = (int*)alloc((size_t)(N + 1) * 4);
    int* cnt             = (int*)alloc((size_t)N * 4);                 // reused as scatter cursor
    int* csr             = (int*)alloc(((size_t)E + 16ull * N + 64) * 4); // padded CSR
    int* perm            = (int*)alloc((size_t)N * 4);                 // degree-sorted node order
    int* hist            = (int*)alloc(32 * 4);
    int* bcur            = (int*)alloc(32 * 4);
    int* bstart          = (int*)alloc((size_t)(B + 2) * 4);
    int  nScanB          = (N + 255) / 256;
    int* bsum            = (int*)alloc((size_t)nScanB * 4);
    int* boff            = (int*)alloc((size_t)nScanB * 4);

    hipMemsetAsync(d_out, 0, (size_t)out_size * sizeof(float), stream);

    int gN = (N + 255) / 256, gE = (E + 255) / 256;
    k_init<<<gN, 256, 0, stream>>>(cnt, bstart, hist, N, B + 1);
    k_count<<<gE, 256, 0, stream>>>(dst, cnt, E, bidx, bstart, N);
    k_prep<<<64, 256, 0, stream>>>(W1, wt1g);
    k_prep<<<64, 256, 0, stream>>>(W2, wt2g);
    k_scanA<<<nScanB, 256, 0, stream>>>(cnt, bsum, N);
    k_scanB<<<1, 256, 0, stream>>>(bsum, boff, nScanB, bstart, N, B);
    k_scanC<<<nScanB, 256, 0, stream>>>(cnt, boff, row_ptr, csr, cnt, hist, N);
    k_scatter<<<gE, 256, 0, stream>>>(src, dst, cnt, csr, E);
    k_bscan<<<1, 1, 0, stream>>>(hist, bcur);
    k_pad<<<gN, 256, 0, stream>>>(row_ptr, cnt, csr, bcur, perm, N);

    int gGemm = (NT + 127) / 128;
    int chunksPerT = (N + 31) / 32;                 // 32 nodes per block
    int chunksPad = ((chunksPerT + 1) / 2) * 2;     // even, for the i&1 swizzle bit
    int gAggFlat = chunksPad * 4;                   // T==4
    k_gemm_mfma<false><<<gGemm, 256, 0, stream>>>(x,   wt1g, as1, ad1, hq, vas, vad, NT);
    k_agg<true ><<<gAggFlat, 256, 0, stream>>>(hq, vas, vad, row_ptr, csr, perm, b1, hb2, N, chunksPerT);
    k_gemm_mfma<true ><<<gGemm, 256, 0, stream>>>(hb2, wt2g, as2, ad2, hq, vas, vad, NT);
    k_agg<false><<<gAggFlat, 256, 0, stream>>>(hq, vas, vad, row_ptr, csr, perm, b2, hb2, N, chunksPerT);
    k_pool<<<dim3(B, 32, T), 128, 0, stream>>>(hb2, bstart, out, N, T);
}

// Round 25
// 323.392 us; speedup vs baseline: 1.0994x; 1.0148x over previous
//
#include <hip/hip_runtime.h>
#include <hip/hip_bf16.h>

#define LEAKY 0.2f

typedef __attribute__((ext_vector_type(8))) short bf16x8;
typedef __attribute__((ext_vector_type(4))) float f32x4;
typedef __attribute__((ext_vector_type(2))) float f32x2;

// ---------------- CSR build (chunk-8 padded), fused setup ----------------

__global__ __launch_bounds__(256) void k_init(int* cnt, int* bstart, int* hist, int n, int nb) {
    int i = blockIdx.x * 256 + threadIdx.x;
    if (i < n) cnt[i] = 1;            // self-loop pre-counted
    if (i < nb) bstart[i] = n;        // batch-boundary init
    if (i < 32) hist[i] = 0;          // degree-bucket histogram
}

// edge count + batch boundary detection (gE blocks >= gN)
__global__ __launch_bounds__(256) void k_count(const int* __restrict__ dst, int* cnt, int e,
                                               const int* __restrict__ bidx, int* bstart, int n) {
    int i = blockIdx.x * 256 + threadIdx.x;
    if (i < e) atomicAdd(&cnt[dst[i]], 1);
    if (i < n) {
        int b = bidx[i];
        if (i == 0 || bidx[i - 1] != b) atomicMin(&bstart[b], i);
    }
}

// block-wide inclusive scan of one value per thread (256 threads)
__device__ inline int block_incl_scan(int v, int* lds) {
    int lane = threadIdx.x & 63, wid = threadIdx.x >> 6;
    int s = v;
#pragma unroll
    for (int o = 1; o < 64; o <<= 1) { int t = __shfl_up(s, o); if (lane >= o) s += t; }
    if (lane == 63) lds[wid] = s;
    __syncthreads();
    int add = 0;
#pragma unroll
    for (int ww = 0; ww < 3; ++ww) if (ww < wid) add += lds[ww];
    return s + add;
}

__global__ __launch_bounds__(256) void k_scanA(const int* __restrict__ cnt, int* bsum, int n) {
    __shared__ int lds[4];
    int i = blockIdx.x * 256 + threadIdx.x;
    int v = (i < n) ? ((cnt[i] + 7) & ~7) : 0;
    int s = block_incl_scan(v, lds);
    if (threadIdx.x == 255) bsum[blockIdx.x] = s;
}

// scan of block sums + batch-boundary backward fill
__global__ __launch_bounds__(256) void k_scanB(int* bsum, int* boff, int nb,
                                               int* bstart, int n, int nbatch) {
    __shared__ int lds[4];
    int i = threadIdx.x;
    int v = (i < nb) ? bsum[i] : 0;
    int s = block_incl_scan(v, lds);
    if (i < nb) boff[i] = s - v;   // exclusive
    if (i == 0) {
        bstart[nbatch] = n;
        for (int b = nbatch - 1; b >= 0; --b)
            if (bstart[b] == n) bstart[b] = bstart[b + 1];
    }
}

// final scan + self-loop placement + cursor init + chunk-count histogram (LDS-aggregated)
__global__ __launch_bounds__(256) void k_scanC(const int* __restrict__ cnt, const int* __restrict__ boff,
                                               int* row_ptr, int* csr, int* cursor, int* hist, int n) {
    __shared__ int lds[4];
    __shared__ int lh[32];
    int tid = threadIdx.x;
    if (tid < 32) lh[tid] = 0;
    int i = blockIdx.x * 256 + tid;
    int v = (i < n) ? ((cnt[i] + 7) & ~7) : 0;
    int s = block_incl_scan(v, lds) + boff[blockIdx.x];
    __syncthreads();
    if (i < n) {
        int excl = s - v;             // row_ptr[i]
        row_ptr[i + 1] = s;
        csr[excl] = i;                // self-loop first
        cursor[i] = excl + 1;
        atomicAdd(&lh[min(v >> 3, 31)], 1);   // LDS atomic (8-chunk count)
    }
    if (i == 0) row_ptr[0] = 0;
    __syncthreads();
    if (tid < 32 && lh[tid]) atomicAdd(&hist[tid], lh[tid]);
}

__global__ __launch_bounds__(256) void k_scatter(const int* __restrict__ src, const int* __restrict__ dst,
                                                 int* cursor, int* csr, int e) {
    int i = blockIdx.x * 256 + threadIdx.x;
    if (i < e) { int p = atomicAdd(&cursor[dst[i]], 1); csr[p] = src[i]; }
}

// exclusive scan of the 32-bucket histogram -> bucket cursors
__global__ void k_bscan(const int* __restrict__ hist, int* bcur) {
    int run = 0;
    for (int b = 0; b < 32; ++b) { bcur[b] = run; run += hist[b]; }
}

// pad slots + degree-bucketed permutation via two-level counting sort
__global__ __launch_bounds__(256) void k_pad(const int* __restrict__ row_ptr, const int* __restrict__ cursor,
                                             int* csr, int* bcur, int* perm, int n) {
    __shared__ int lh[32];    // block-local bucket counts
    __shared__ int lbase[32]; // reserved global base per bucket
    int tid = threadIdx.x;
    if (tid < 32) lh[tid] = 0;
    __syncthreads();
    int i = blockIdx.x * 256 + tid;
    int bkt = 0, lpos = 0, b0 = 0, p = 0, e = 0;
    if (i < n) {
        b0 = row_ptr[i]; p = cursor[i]; e = row_ptr[i + 1];
        bkt = min((e - b0) >> 3, 31);
        lpos = atomicAdd(&lh[bkt], 1);        // LDS atomic (fast)
    }
    __syncthreads();
    if (tid < 32 && lh[tid]) lbase[tid] = atomicAdd(&bcur[tid], lh[tid]);
    __syncthreads();
    if (i < n) {
        perm[lbase[bkt] + lpos] = i;
        int v = i | 0x80000000;
        for (; p < e; ++p) csr[p] = v;
    }
}

// round-nearest-even f32 -> bf16 (as ushort)
__device__ inline unsigned short bf16r(float x) {
    unsigned int u = __float_as_uint(x);
    u += 0x7fffu + ((u >> 16) & 1u);
    return (unsigned short)(u >> 16);
}

// round-nearest-even pack of two f32 into one uint (2×bf16, lo|hi<<16)
__device__ inline unsigned int bfpair(float lo, float hi) {
    unsigned int ul = __float_as_uint(lo); ul += 0x7fffu + ((ul >> 16) & 1u);
    unsigned int uh = __float_as_uint(hi); uh += 0x7fffu + ((uh >> 16) & 1u);
    return (ul >> 16) | (uh & 0xffff0000u);
}

// one-time: W[k][n] f32 -> pre-swizzled bf16 W^T global table
// wtg[(n*16 + (kg ^ (n&15)))*8 + kr],  kg=k>>3, kr=k&7  (matches GEMM read formula)
__global__ __launch_bounds__(256) void k_prep(const float* __restrict__ W, unsigned short* __restrict__ wtg) {
    int idx = blockIdx.x * 256 + threadIdx.x;   // 0..16383
    int k = idx >> 7, n = idx & 127;
    int kg = k >> 3, kr = k & 7;
    wtg[(n * 16 + (kg ^ (n & 15))) * 8 + kr] = bf16r(W[k * 128 + n]);
}

// ---------------- MFMA GEMM + attention logits (batched over all T snapshots) ----------------
// OPERAND-SWAPPED: D = mfma(W_frag, X_frag). ALL A-fragment loads (2 mi x 4 ks) hoisted
// ahead of staging+barrier -> 16 concurrent global loads per thread (r24 issued them
// inside the K-loop: 4 serial latency round-trips, MfmaUtil 3.8%, 0.8 TB/s).
template <bool ABF16>
__global__ __launch_bounds__(256) void k_gemm_mfma(
    const void* __restrict__ Asrc, const unsigned short* __restrict__ wtg,
    const float* __restrict__ asrc, const float* __restrict__ adst,
    unsigned char* __restrict__ hq, float* __restrict__ vas, float* __restrict__ vad,
    int nrows)
{
    __shared__ unsigned short Wt[128 * 128];  // swizzled [n][k] bf16, 32 KB
    int tid = threadIdx.x;
    int lane = tid & 63, wv = tid >> 6;
    int row0 = blockIdx.x * 128;
    int c0 = lane & 15, g = lane >> 4;

    int rA[2];
#pragma unroll
    for (int mi = 0; mi < 2; ++mi)
        rA[mi] = min(row0 + wv * 32 + mi * 16 + c0, nrows - 1);

    // ---- issue ALL A loads (registers) + staging loads, then write LDS, then barrier ----
    bf16x8 af[2][4];
    uint4 stg[8];
    {
        const uint4* s4 = (const uint4*)wtg;
#pragma unroll
        for (int i = 0; i < 8; ++i) stg[i] = s4[tid + i * 256];
    }
    if (ABF16) {
#pragma unroll
        for (int mi = 0; mi < 2; ++mi)
#pragma unroll
            for (int ks = 0; ks < 4; ++ks)
                af[mi][ks] = *(const bf16x8*)((const unsigned short*)Asrc + (size_t)rA[mi] * 128 + ks * 32 + g * 8);
    } else {
        float4 raw[2][4][2];
#pragma unroll
        for (int mi = 0; mi < 2; ++mi)
#pragma unroll
            for (int ks = 0; ks < 4; ++ks) {
                const float4* ap = (const float4*)((const float*)Asrc + (size_t)rA[mi] * 128 + ks * 32 + g * 8);
                raw[mi][ks][0] = ap[0];
                raw[mi][ks][1] = ap[1];
            }
#pragma unroll
        for (int mi = 0; mi < 2; ++mi)
#pragma unroll
            for (int ks = 0; ks < 4; ++ks) {
                float4 f0 = raw[mi][ks][0], f1 = raw[mi][ks][1];
                uint4 p = make_uint4(bfpair(f0.x, f0.y), bfpair(f0.z, f0.w),
                                     bfpair(f1.x, f1.y), bfpair(f1.z, f1.w));
                af[mi][ks] = *(bf16x8*)&p;
            }
    }
    {
        uint4* d4 = (uint4*)Wt;
#pragma unroll
        for (int i = 0; i < 8; ++i) d4[tid + i * 256] = stg[i];
    }
    __syncthreads();

    f32x4 acc[2][8];
#pragma unroll
    for (int mi = 0; mi < 2; ++mi)
#pragma unroll
        for (int ni = 0; ni < 8; ++ni)
#pragma unroll
            for (int q = 0; q < 4; ++q) acc[mi][ni][q] = 0.f;

#pragma unroll
    for (int ks = 0; ks < 4; ++ks) {
        int kgbase = ks * 4;
        bf16x8 bfr[8];
#pragma unroll
        for (int ni = 0; ni < 8; ++ni) {
            int n = ni * 16 + c0;
            bfr[ni] = *(const bf16x8*)&Wt[(n * 16 + ((kgbase + g) ^ c0)) * 8];
        }
#pragma unroll
        for (int mi = 0; mi < 2; ++mi)
#pragma unroll
            for (int ni = 0; ni < 8; ++ni)
                acc[mi][ni] = __builtin_amdgcn_mfma_f32_16x16x32_bf16(bfr[ni], af[mi][ks], acc[mi][ni], 0, 0, 0);
    }

    // ---- epilogue ----
    float4 as4[8], ad4[8];
#pragma unroll
    for (int ni = 0; ni < 8; ++ni) {
        as4[ni] = *(const float4*)&asrc[ni * 16 + g * 4];
        ad4[ni] = *(const float4*)&adst[ni * 16 + g * 4];
    }
#pragma unroll
    for (int mi = 0; mi < 2; ++mi) {
        int node = row0 + wv * 32 + mi * 16 + c0;
        bool ok = node < nrows;
        float s = 0.f, d = 0.f;
        unsigned packs[8];
#pragma unroll
        for (int ni = 0; ni < 8; ++ni) {
            f32x4 vv = acc[mi][ni];
            s = fmaf(vv[0], as4[ni].x, fmaf(vv[1], as4[ni].y, fmaf(vv[2], as4[ni].z, fmaf(vv[3], as4[ni].w, s))));
            d = fmaf(vv[0], ad4[ni].x, fmaf(vv[1], ad4[ni].y, fmaf(vv[2], ad4[ni].z, fmaf(vv[3], ad4[ni].w, d))));
            unsigned p0 = (unsigned)__builtin_amdgcn_cvt_pk_fp8_f32(vv[0], vv[1], 0, false);
            packs[ni] = (unsigned)__builtin_amdgcn_cvt_pk_fp8_f32(vv[2], vv[3], (int)p0, true);
        }
        s += __shfl_xor(s, 16); s += __shfl_xor(s, 32);
        d += __shfl_xor(d, 16); d += __shfl_xor(d, 32);
        if (ok) {
            if (g == 0) { vas[node] = s; vad[node] = d; }
#pragma unroll
            for (int ni = 0; ni < 8; ++ni)
                *(unsigned*)&hq[(size_t)node * 128 + ni * 16 + g * 4] = packs[ni];
        }
    }
}

// ---------------- aggregation: 8-lane group per dst node, chunk-8, degree-bucketed ----------------
template <bool RELU>
__global__ __launch_bounds__(256) void k_agg(const unsigned char* __restrict__ hq,
                                             const float* __restrict__ vas,
                                             const float* __restrict__ vad,
                                             const int* __restrict__ row_ptr,
                                             const int* __restrict__ csr,
                                             const int* __restrict__ perm,
                                             const float* __restrict__ bias,
                                             unsigned int* __restrict__ outb,
                                             int n, int chunksPerT) {
    int i = blockIdx.x;
    int slot = i & 7;
    int t = slot >> 1;
    int chunk = ((i >> 3) << 1) | (slot & 1);
    if (chunk >= chunksPerT) return;
    int tid = threadIdx.x;
    int grp = tid >> 3, l = tid & 7;     // 32 groups of 8 lanes
    int idx = chunk * 32 + grp;
    if (idx >= n) return;
    int w = perm[idx];
    unsigned int tbase = (unsigned int)t * (unsigned int)n;
    unsigned int g = tbase + (unsigned int)w;
    int beg = row_ptr[w], end = row_ptr[w + 1];
    float advl = vad[g];

    f32x2 acc2[8];
#pragma unroll
    for (int q = 0; q < 8; ++q) { acc2[q].x = 0.f; acc2[q].y = 0.f; }
    float zp = 0.f;

    for (int c = beg; c < end; c += 8) {
        int raw = csr[c + l];                       // coalesced (8 consecutive)
        unsigned int s_l = tbase + (unsigned int)(raw & 0x7fffffff);
        float e = vas[s_l] + advl;
        e = e > 0.f ? e : LEAKY * e;
        float w_l = (raw >= 0) ? __expf(e) : 0.f;   // pads contribute 0
        zp += w_l;

        unsigned int ofs[8]; float wt[8];
#pragma unroll
        for (int q = 0; q < 8; ++q) {
            ofs[q] = __shfl(s_l, q, 8) * 128u + (unsigned int)(l * 16);  // 32-bit byte offset
            wt[q] = __shfl(w_l, q, 8);
        }
        uint4 v[8];
#pragma unroll
        for (int q = 0; q < 8; ++q)
            v[q] = *(const uint4*)&hq[ofs[q]];
#pragma unroll
        for (int q = 0; q < 8; ++q) {
            f32x2 w2; w2.x = wt[q]; w2.y = wt[q];
            acc2[0] = __builtin_elementwise_fma(w2, __builtin_amdgcn_cvt_pk_f32_fp8(v[q].x, false), acc2[0]);
            acc2[1] = __builtin_elementwise_fma(w2, __builtin_amdgcn_cvt_pk_f32_fp8(v[q].x, true),  acc2[1]);
            acc2[2] = __builtin_elementwise_fma(w2, __builtin_amdgcn_cvt_pk_f32_fp8(v[q].y, false), acc2[2]);
            acc2[3] = __builtin_elementwise_fma(w2, __builtin_amdgcn_cvt_pk_f32_fp8(v[q].y, true),  acc2[3]);
            acc2[4] = __builtin_elementwise_fma(w2, __builtin_amdgcn_cvt_pk_f32_fp8(v[q].z, false), acc2[4]);
            acc2[5] = __builtin_elementwise_fma(w2, __builtin_amdgcn_cvt_pk_f32_fp8(v[q].z, true),  acc2[5]);
            acc2[6] = __builtin_elementwise_fma(w2, __builtin_amdgcn_cvt_pk_f32_fp8(v[q].w, false), acc2[6]);
            acc2[7] = __builtin_elementwise_fma(w2, __builtin_amdgcn_cvt_pk_f32_fp8(v[q].w, true),  acc2[7]);
        }
    }

    float z = zp;
    z += __shfl_xor(z, 1, 8);
    z += __shfl_xor(z, 2, 8);
    z += __shfl_xor(z, 4, 8);
    float inv = 1.0f / z;

    const float4* bias4 = (const float4*)&bias[l * 16];
    unsigned u[8];
#pragma unroll
    for (int j = 0; j < 4; ++j) {
        float4 bb = bias4[j];
        float o0 = fmaf(acc2[2 * j].x, inv, bb.x);
        float o1 = fmaf(acc2[2 * j].y, inv, bb.y);
        float o2 = fmaf(acc2[2 * j + 1].x, inv, bb.z);
        float o3 = fmaf(acc2[2 * j + 1].y, inv, bb.w);
        if (RELU) {
            o0 = fmaxf(o0, 0.f); o1 = fmaxf(o1, 0.f); o2 = fmaxf(o2, 0.f); o3 = fmaxf(o3, 0.f);
        }
        u[2 * j]     = bfpair(o0, o1);
        u[2 * j + 1] = bfpair(o2, o3);
    }
    *(uint4*)&outb[(size_t)g * 64 + l * 8]     = make_uint4(u[0], u[1], u[2], u[3]);
    *(uint4*)&outb[(size_t)g * 64 + l * 8 + 4] = make_uint4(u[4], u[5], u[6], u[7]);
}

// ---------------- batch mean pool (batch_idx sorted), bf16 t-major input ----------------
__global__ __launch_bounds__(128) void k_pool(const unsigned int* __restrict__ h,
                                              const int* __restrict__ bstart,
                                              float* __restrict__ out, int n, int T) {
    int b = blockIdx.x;
    int chunk = blockIdx.y;
    int t = blockIdx.z;
    int f = threadIdx.x;
    int s = bstart[b], e = bstart[b + 1];
    int cnt = e - s;
    if (cnt <= 0) return;
    int len = (cnt + 31) / 32;
    int cs = s + chunk * len;
    int ce = min(cs + len, e);
    if (cs >= ce) return;
    const unsigned int* ht = h + (size_t)t * n * 64;
    float acc = 0.f;
    for (int nidx = cs; nidx < ce; ++nidx) {
        unsigned int v = ht[(size_t)nidx * 64 + (f >> 1)];
        acc += __uint_as_float((f & 1) ? (v & 0xffff0000u) : (v << 16));
    }
    atomicAdd(&out[(size_t)(b * T + t) * 128 + f], acc / (float)cnt);
}

// ---------------- launch ----------------

extern "C" void kernel_launch(void* const* d_in, const int* in_sizes, int n_in,
                              void* d_out, int out_size, void* d_ws, size_t ws_size,
                              hipStream_t stream) {
    const float* x    = (const float*)d_in[0];
    const int*   ei   = (const int*)d_in[1];
    const int*   bidx = (const int*)d_in[2];
    const float* W1   = (const float*)d_in[3];
    const float* as1  = (const float*)d_in[4];
    const float* ad1  = (const float*)d_in[5];
    const float* b1   = (const float*)d_in[6];
    const float* W2   = (const float*)d_in[7];
    const float* as2  = (const float*)d_in[8];
    const float* ad2  = (const float*)d_in[9];
    const float* b2   = (const float*)d_in[10];
    float* out = (float*)d_out;

    const int E = in_sizes[1] / 2;
    const int N = in_sizes[2];
    const int T = in_sizes[0] / (N * 128);   // == 4 (swizzle assumes 4)
    const int B = out_size / (T * 128);
    const int* src = ei;
    const int* dst = ei + E;
    const int NT = N * T;

    char* wsp = (char*)d_ws;
    auto alloc = [&](size_t bytes) { void* p = wsp; wsp += (bytes + 255) / 256 * 256; return p; };
    unsigned char* hq    = (unsigned char*)alloc((size_t)NT * 128);    // fp8 GEMM out (gather table)
    unsigned int* hb2    = (unsigned int*)alloc((size_t)NT * 64 * 4);  // bf16 agg out, t-major
    float* vas           = (float*)alloc((size_t)NT * 4);
    float* vad           = (float*)alloc((size_t)NT * 4);
    unsigned short* wt1g = (unsigned short*)alloc(128 * 128 * 2);      // pre-swizzled bf16 W1^T
    unsigned short* wt2g = (unsigned short*)alloc(128 * 128 * 2);      // pre-swizzled bf16 W2^T
    int* row_ptr         = (int*)alloc((size_t)(N + 1) * 4);
    int* cnt             = (int*)alloc((size_t)N * 4);                 // reused as scatter cursor
    int* csr             = (int*)alloc(((size_t)E + 16ull * N + 64) * 4); // padded CSR
    int* perm            = (int*)alloc((size_t)N * 4);                 // degree-sorted node order
    int* hist            = (int*)alloc(32 * 4);
    int* bcur            = (int*)alloc(32 * 4);
    int* bstart          = (int*)alloc((size_t)(B + 2) * 4);
    int  nScanB          = (N + 255) / 256;
    int* bsum            = (int*)alloc((size_t)nScanB * 4);
    int* boff            = (int*)alloc((size_t)nScanB * 4);

    hipMemsetAsync(d_out, 0, (size_t)out_size * sizeof(float), stream);

    int gN = (N + 255) / 256, gE = (E + 255) / 256;
    k_init<<<gN, 256, 0, stream>>>(cnt, bstart, hist, N, B + 1);
    k_count<<<gE, 256, 0, stream>>>(dst, cnt, E, bidx, bstart, N);
    k_prep<<<64, 256, 0, stream>>>(W1, wt1g);
    k_prep<<<64, 256, 0, stream>>>(W2, wt2g);
    k_scanA<<<nScanB, 256, 0, stream>>>(cnt, bsum, N);
    k_scanB<<<1, 256, 0, stream>>>(bsum, boff, nScanB, bstart, N, B);
    k_scanC<<<nScanB, 256, 0, stream>>>(cnt, boff, row_ptr, csr, cnt, hist, N);
    k_scatter<<<gE, 256, 0, stream>>>(src, dst, cnt, csr, E);
    k_bscan<<<1, 1, 0, stream>>>(hist, bcur);
    k_pad<<<gN, 256, 0, stream>>>(row_ptr, cnt, csr, bcur, perm, N);

    int gGemm = (NT + 127) / 128;
    int chunksPerT = (N + 31) / 32;                 // 32 nodes per block
    int chunksPad = ((chunksPerT + 1) / 2) * 2;     // even, for the i&1 swizzle bit
    int gAggFlat = chunksPad * 4;                   // T==4
    k_gemm_mfma<false><<<gGemm, 256, 0, stream>>>(x,   wt1g, as1, ad1, hq, vas, vad, NT);
    k_agg<true ><<<gAggFlat, 256, 0, stream>>>(hq, vas, vad, row_ptr, csr, perm, b1, hb2, N, chunksPerT);
    k_gemm_mfma<true ><<<gGemm, 256, 0, stream>>>(hb2, wt2g, as2, ad2, hq, vas, vad, NT);
    k_agg<false><<<gAggFlat, 256, 0, stream>>>(hq, vas, vad, row_ptr, csr, perm, b2, hb2, N, chunksPerT);
    k_pool<<<dim3(B, 32, T), 128, 0, stream>>>(hb2, bstart, out, N, T);
}